// Round 9
// baseline (17.581 us; speedup 1.0000x reference)
//
#include <hip/hip_runtime.h>

#define NF     26
#define CARD   100
#define EDIM   16
#define NDENSE 13
#define COLS   2626   // NF*(CARD+1)
#define NLOOK  2600   // NF*CARD
#define NT     1024
#define G      4      // batch rows per block
#define NQUAD  256    // NT/4
#define MAIN_ITERS 10 // 2600 = 256*10 + 40
#define TAIL_QUADS 40
#define NWAVE  16     // NT/64

__global__ __launch_bounds__(NT) void fm_kernel(
    const int*   __restrict__ sparse,   // B x 2626 (int32)
    const float* __restrict__ dense,    // B x 13
    const float* __restrict__ lin_t,    // 2600
    const float* __restrict__ emb_t,    // 2600 x 16
    const float* __restrict__ lw,       // 39
    const float* __restrict__ lb,       // 1
    float*       __restrict__ out)      // B
{
    __shared__ unsigned cnt[G * NLOOK];          // 41.6 KB
    __shared__ float    s_w[NF + NDENSE];
    __shared__ float    red[NWAVE][G][EDIM + 2]; // 4.6 KB

    const int blk = blockIdx.x;
    const int t   = threadIdx.x;

    // ---- phase 0: zero counts, stage weights ----
    for (int i = t; i < G * NLOOK; i += NT) cnt[i] = 0u;
    if (t < NF + NDENSE) s_w[t] = lw[t];
    __syncthreads();

    // ---- phase 1: build count vectors (scattered LDS atomics) ----
    #pragma unroll
    for (int g = 0; g < G; ++g) {
        const int* row = sparse + (size_t)(G * blk + g) * COLS;
        for (int i = t; i < NLOOK; i += NT) {
            const int f   = i / CARD;            // const-div -> magic mul
            const int idx = row[i + f];          // col = f*101 + (i - f*100)
            atomicAdd(&cnt[g * NLOOK + f * CARD + idx], 1u);
        }
    }
    __syncthreads();

    // ---- phase 2: dense stream of the table, weighted by counts ----
    const int quad = t >> 2;   // 0..255
    const int c    = t & 3;    // 16B chunk of the 64B embedding row

    float4 s[G];
    float  sos[G], lin[G];
    #pragma unroll
    for (int g = 0; g < G; ++g) {
        s[g] = make_float4(0.f, 0.f, 0.f, 0.f);
        sos[g] = 0.f; lin[g] = 0.f;
    }

    #pragma unroll
    for (int i = 0; i < MAIN_ITERS; ++i) {
        const int r = quad + i * NQUAD;
        const float4 v = *reinterpret_cast<const float4*>(emb_t + (r << 4) + (c << 2));
        const float lt  = lin_t[r];
        const int   f   = r / CARD;
        const float lv  = lt * s_w[f];
        const float ssq = v.x*v.x + v.y*v.y + v.z*v.z + v.w*v.w;
        #pragma unroll
        for (int g = 0; g < G; ++g) {
            const float fc = (float)cnt[g * NLOOK + r];
            s[g].x += fc * v.x; s[g].y += fc * v.y;
            s[g].z += fc * v.z; s[g].w += fc * v.w;
            sos[g] += fc * ssq;
            lin[g] += fc * lv;   // 4x redundant per quad; scaled later
        }
    }
    if (quad < TAIL_QUADS) {     // rows 2560..2599
        const int r = quad + MAIN_ITERS * NQUAD;
        const float4 v = *reinterpret_cast<const float4*>(emb_t + (r << 4) + (c << 2));
        const float lt  = lin_t[r];
        const int   f   = r / CARD;
        const float lv  = lt * s_w[f];
        const float ssq = v.x*v.x + v.y*v.y + v.z*v.z + v.w*v.w;
        #pragma unroll
        for (int g = 0; g < G; ++g) {
            const float fc = (float)cnt[g * NLOOK + r];
            s[g].x += fc * v.x; s[g].y += fc * v.y;
            s[g].z += fc * v.z; s[g].w += fc * v.w;
            sos[g] += fc * ssq;
            lin[g] += fc * lv;
        }
    }

    // ---- phase 3: reduction (wave = 64 lanes) ----
    #pragma unroll
    for (int off = 32; off >= 4; off >>= 1) {
        #pragma unroll
        for (int g = 0; g < G; ++g) {
            s[g].x += __shfl_down(s[g].x, off, 64);
            s[g].y += __shfl_down(s[g].y, off, 64);
            s[g].z += __shfl_down(s[g].z, off, 64);
            s[g].w += __shfl_down(s[g].w, off, 64);
            sos[g] += __shfl_down(sos[g], off, 64);
            lin[g] += __shfl_down(lin[g], off, 64);
        }
    }
    #pragma unroll
    for (int g = 0; g < G; ++g) {
        sos[g] += __shfl_down(sos[g], 2, 64); lin[g] += __shfl_down(lin[g], 2, 64);
        sos[g] += __shfl_down(sos[g], 1, 64); lin[g] += __shfl_down(lin[g], 1, 64);
    }

    const int wave = t >> 6;   // 0..15
    const int lane = t & 63;
    if (lane < 4) {            // lane L holds chunk L (elements 4L..4L+3)
        #pragma unroll
        for (int g = 0; g < G; ++g) {
            red[wave][g][lane*4+0] = s[g].x; red[wave][g][lane*4+1] = s[g].y;
            red[wave][g][lane*4+2] = s[g].z; red[wave][g][lane*4+3] = s[g].w;
        }
    }
    if (lane == 0) {
        #pragma unroll
        for (int g = 0; g < G; ++g) {
            red[wave][g][EDIM] = sos[g]; red[wave][g][EDIM+1] = lin[g];
        }
    }
    __syncthreads();

    if (t < G) {
        const int g = t;
        float pair = 0.f;
        #pragma unroll
        for (int e = 0; e < EDIM; ++e) {
            float fs = 0.f;
            #pragma unroll
            for (int w = 0; w < NWAVE; ++w) fs += red[w][g][e];
            pair += fs * fs;
        }
        float fsos = 0.f, flin = 0.f;
        #pragma unroll
        for (int w = 0; w < NWAVE; ++w) { fsos += red[w][g][EDIM]; flin += red[w][g][EDIM+1]; }
        flin *= 0.25f;                       // quad redundancy
        pair = 0.5f * (pair - fsos);

        const int b = G * blk + g;
        float acc = flin + lb[0];
        const float* drow = dense + (size_t)b * NDENSE;
        #pragma unroll
        for (int dd = 0; dd < NDENSE; ++dd) acc += drow[dd] * s_w[NF + dd];

        out[b] = acc + pair;
    }
}

extern "C" void kernel_launch(void* const* d_in, const int* in_sizes, int n_in,
                              void* d_out, int out_size, void* d_ws, size_t ws_size,
                              hipStream_t stream) {
    const int*   sparse = (const int*)  d_in[0];
    const float* dense  = (const float*)d_in[1];
    const float* lin_t  = (const float*)d_in[2];
    const float* emb_t  = (const float*)d_in[3];
    const float* lw     = (const float*)d_in[4];
    const float* lb     = (const float*)d_in[5];
    float* out = (float*)d_out;

    const int B = out_size;  // 1024
    fm_kernel<<<B / G, NT, 0, stream>>>(sparse, dense, lin_t, emb_t, lw, lb, out);
}

// Round 10
// 15.510 us; speedup vs baseline: 1.1335x; 1.1335x over previous
//
#include <hip/hip_runtime.h>

#define NF     26
#define CARD   100
#define EDIM   16
#define NDENSE 13
#define COLS   2626   // NF*(CARD+1)
#define NLOOK  2600   // NF*CARD
#define NT     512
#define G      2      // batch rows per block
#define NQUAD  128    // NT/4
#define MAIN_ITERS 20 // 2600 = 128*20 + 40
#define TAIL_QUADS 40
#define NWAVE  8

__global__ __launch_bounds__(NT) void fm_kernel(
    const int*   __restrict__ sparse,   // B x 2626 (int32)
    const float* __restrict__ dense,    // B x 13
    const float* __restrict__ lin_t,    // 2600
    const float* __restrict__ emb_t,    // 2600 x 16
    const float* __restrict__ lw,       // 39
    const float* __restrict__ lb,       // 1
    float*       __restrict__ out)      // B
{
    __shared__ unsigned cnt[G * NLOOK];     // 20.8 KB
    __shared__ float    lv[NLOOK];          // 10.4 KB: lin_t[r]*w[f(r)]
    __shared__ float    s_w[NF + NDENSE];
    __shared__ float    red[NWAVE][G][EDIM + 2];

    const int blk = blockIdx.x;
    const int t   = threadIdx.x;

    // ---- phase 0: zero counts, stage weights ----
    for (int i = t; i < G * NLOOK; i += NT) cnt[i] = 0u;
    if (t < NF + NDENSE) s_w[t] = lw[t];
    __syncthreads();

    // ---- phase 1a: precombine linear table with feature weights ----
    for (int r = t; r < NLOOK; r += NT) {
        const int f = r / CARD;                  // magic-mul
        lv[r] = lin_t[r] * s_w[f];
    }

    // ---- phase 1b: build count vectors (int2 loads over raw columns) ----
    #pragma unroll
    for (int g = 0; g < G; ++g) {
        const int* row = sparse + (size_t)(G * blk + g) * COLS;
        for (int p = t; p < COLS / 2; p += NT) {     // 1313 int2 loads
            const int2 v = reinterpret_cast<const int2*>(row)[p];
            {
                const int cc = 2 * p;
                const int f  = cc / (CARD + 1);      // magic-mul
                const int j  = cc - f * (CARD + 1);
                if (j < CARD) atomicAdd(&cnt[g * NLOOK + f * CARD + v.x], 1u);
            }
            {
                const int cc = 2 * p + 1;
                const int f  = cc / (CARD + 1);
                const int j  = cc - f * (CARD + 1);
                if (j < CARD) atomicAdd(&cnt[g * NLOOK + f * CARD + v.y], 1u);
            }
        }
    }

    // ---- phase 2 prologue: issue first table load BEFORE the barrier ----
    const int quad = t >> 2;   // 0..127
    const int c    = t & 3;    // 16B chunk of the 64B embedding row
    float4 vcur = *reinterpret_cast<const float4*>(emb_t + (quad << 4) + (c << 2));

    __syncthreads();           // counts + lv ready; vcur in flight over the drain

    float4 s0 = make_float4(0.f, 0.f, 0.f, 0.f);
    float4 s1 = make_float4(0.f, 0.f, 0.f, 0.f);
    float sos0 = 0.f, sos1 = 0.f, lin0 = 0.f, lin1 = 0.f;

    // ---- phase 2: dense stream, software-pipelined ----
    #pragma unroll 4
    for (int i = 0; i < MAIN_ITERS; ++i) {
        const int r = quad + i * NQUAD;
        float4 vnext;
        if (i + 1 < MAIN_ITERS) {
            const int rn = quad + (i + 1) * NQUAD;
            vnext = *reinterpret_cast<const float4*>(emb_t + (rn << 4) + (c << 2));
        }
        const float lvr = lv[r];
        const float fc0 = (float)cnt[r];
        const float fc1 = (float)cnt[NLOOK + r];
        const float ssq = vcur.x*vcur.x + vcur.y*vcur.y + vcur.z*vcur.z + vcur.w*vcur.w;
        s0.x += fc0 * vcur.x; s0.y += fc0 * vcur.y; s0.z += fc0 * vcur.z; s0.w += fc0 * vcur.w;
        s1.x += fc1 * vcur.x; s1.y += fc1 * vcur.y; s1.z += fc1 * vcur.z; s1.w += fc1 * vcur.w;
        sos0 += fc0 * ssq; sos1 += fc1 * ssq;
        lin0 += fc0 * lvr; lin1 += fc1 * lvr;    // 4x redundant per quad; scaled later
        if (i + 1 < MAIN_ITERS) vcur = vnext;
    }
    if (quad < TAIL_QUADS) {                     // rows 2560..2599
        const int r = quad + MAIN_ITERS * NQUAD;
        const float4 v = *reinterpret_cast<const float4*>(emb_t + (r << 4) + (c << 2));
        const float lvr = lv[r];
        const float fc0 = (float)cnt[r];
        const float fc1 = (float)cnt[NLOOK + r];
        const float ssq = v.x*v.x + v.y*v.y + v.z*v.z + v.w*v.w;
        s0.x += fc0 * v.x; s0.y += fc0 * v.y; s0.z += fc0 * v.z; s0.w += fc0 * v.w;
        s1.x += fc1 * v.x; s1.y += fc1 * v.y; s1.z += fc1 * v.z; s1.w += fc1 * v.w;
        sos0 += fc0 * ssq; sos1 += fc1 * ssq;
        lin0 += fc0 * lvr; lin1 += fc1 * lvr;
    }

    // ---- phase 3: reduction (wave = 64 lanes) ----
    #pragma unroll
    for (int off = 32; off >= 4; off >>= 1) {
        s0.x += __shfl_down(s0.x, off, 64); s0.y += __shfl_down(s0.y, off, 64);
        s0.z += __shfl_down(s0.z, off, 64); s0.w += __shfl_down(s0.w, off, 64);
        s1.x += __shfl_down(s1.x, off, 64); s1.y += __shfl_down(s1.y, off, 64);
        s1.z += __shfl_down(s1.z, off, 64); s1.w += __shfl_down(s1.w, off, 64);
        sos0 += __shfl_down(sos0, off, 64); sos1 += __shfl_down(sos1, off, 64);
        lin0 += __shfl_down(lin0, off, 64); lin1 += __shfl_down(lin1, off, 64);
    }
    sos0 += __shfl_down(sos0, 2, 64); sos1 += __shfl_down(sos1, 2, 64);
    lin0 += __shfl_down(lin0, 2, 64); lin1 += __shfl_down(lin1, 2, 64);
    sos0 += __shfl_down(sos0, 1, 64); sos1 += __shfl_down(sos1, 1, 64);
    lin0 += __shfl_down(lin0, 1, 64); lin1 += __shfl_down(lin1, 1, 64);

    const int wave = t >> 6;
    const int lane = t & 63;
    if (lane < 4) {            // lane L holds chunk L (elements 4L..4L+3)
        red[wave][0][lane*4+0] = s0.x; red[wave][0][lane*4+1] = s0.y;
        red[wave][0][lane*4+2] = s0.z; red[wave][0][lane*4+3] = s0.w;
        red[wave][1][lane*4+0] = s1.x; red[wave][1][lane*4+1] = s1.y;
        red[wave][1][lane*4+2] = s1.z; red[wave][1][lane*4+3] = s1.w;
    }
    if (lane == 0) {
        red[wave][0][EDIM] = sos0; red[wave][0][EDIM+1] = lin0;
        red[wave][1][EDIM] = sos1; red[wave][1][EDIM+1] = lin1;
    }
    __syncthreads();

    if (t < G) {
        const int g = t;
        float pair = 0.f;
        #pragma unroll
        for (int e = 0; e < EDIM; ++e) {
            float fs = 0.f;
            #pragma unroll
            for (int w = 0; w < NWAVE; ++w) fs += red[w][g][e];
            pair += fs * fs;
        }
        float fsos = 0.f, flin = 0.f;
        #pragma unroll
        for (int w = 0; w < NWAVE; ++w) { fsos += red[w][g][EDIM]; flin += red[w][g][EDIM+1]; }
        flin *= 0.25f;                       // quad redundancy
        pair = 0.5f * (pair - fsos);

        const int b = G * blk + g;
        float acc = flin + lb[0];
        const float* drow = dense + (size_t)b * NDENSE;
        #pragma unroll
        for (int dd = 0; dd < NDENSE; ++dd) acc += drow[dd] * s_w[NF + dd];

        out[b] = acc + pair;
    }
}

extern "C" void kernel_launch(void* const* d_in, const int* in_sizes, int n_in,
                              void* d_out, int out_size, void* d_ws, size_t ws_size,
                              hipStream_t stream) {
    const int*   sparse = (const int*)  d_in[0];
    const float* dense  = (const float*)d_in[1];
    const float* lin_t  = (const float*)d_in[2];
    const float* emb_t  = (const float*)d_in[3];
    const float* lw     = (const float*)d_in[4];
    const float* lb     = (const float*)d_in[5];
    float* out = (float*)d_out;

    const int B = out_size;  // 1024
    fm_kernel<<<B / G, NT, 0, stream>>>(sparse, dense, lin_t, emb_t, lw, lb, out);
}